// Round 1
// baseline (57055.731 us; speedup 1.0000x reference)
//
#include <hip/hip_runtime.h>

#define NN 100000
#define NE 3200000
#define D 128
#define ND (NN * D)
#define ND4 (ND / 4)
#define KMAX 10

__global__ __launch_bounds__(256) void deg_kernel(const int* __restrict__ row,
                                                  int* __restrict__ deg) {
    int e = blockIdx.x * 256 + threadIdx.x;
    if (e < NE) atomicAdd(&deg[row[e]], 1);
}

__global__ __launch_bounds__(256) void dis_kernel(const int* __restrict__ deg,
                                                  float* __restrict__ dis) {
    int i = blockIdx.x * 256 + threadIdx.x;
    if (i < NN) {
        int d = deg[i];
        dis[i] = d > 0 ? rsqrtf((float)d) : 0.0f;
    }
}

__global__ __launch_bounds__(256) void norm_kernel(const int* __restrict__ row,
                                                   const int* __restrict__ col,
                                                   const float* __restrict__ dis,
                                                   float* __restrict__ nrm) {
    int e = blockIdx.x * 256 + threadIdx.x;
    if (e < NE) nrm[e] = dis[row[e]] * dis[col[e]];
}

// S[row[e], :] += norm[e] * y[col[e], :]
// 32 threads per edge, 4 floats (one float4) per thread.
__global__ __launch_bounds__(256) void spmv_kernel(const int* __restrict__ row,
                                                   const int* __restrict__ col,
                                                   const float* __restrict__ nrm,
                                                   const float* __restrict__ y,
                                                   float* __restrict__ S) {
    int tid = blockIdx.x * 256 + threadIdx.x;
    int e = tid >> 5;
    int g = tid & 31;
    if (e >= NE) return;
    int r = row[e];
    int c = col[e];
    float w = nrm[e];
    const float4* yv = (const float4*)(y + (long long)c * D);
    float4 v = yv[g];
    float* dst = S + (long long)r * D + g * 4;
    atomicAdd(dst + 0, w * v.x);
    atomicAdd(dst + 1, w * v.y);
    atomicAdd(dst + 2, w * v.z);
    atomicAdd(dst + 3, w * v.w);
}

// P1 = u1*x + u2*S  (in place over S); out = alpha[0]*x + beta[1]*gamma[0]*P1
__global__ __launch_bounds__(256) void combine1_kernel(const float4* __restrict__ x,
                                                       float4* __restrict__ S,
                                                       const float* __restrict__ alpha,
                                                       const float* __restrict__ beta,
                                                       const float* __restrict__ gamma,
                                                       float4* __restrict__ out,
                                                       float u1, float u2) {
    int i = blockIdx.x * 256 + threadIdx.x;
    if (i >= ND4) return;
    float a0 = alpha[0];
    float bg = beta[1] * gamma[0];
    float4 xv = x[i];
    float4 sv = S[i];
    float4 p1;
    p1.x = u1 * xv.x + u2 * sv.x;
    p1.y = u1 * xv.y + u2 * sv.y;
    p1.z = u1 * xv.z + u2 * sv.z;
    p1.w = u1 * xv.w + u2 * sv.w;
    S[i] = p1;
    float4 o;
    o.x = a0 * xv.x + bg * p1.x;
    o.y = a0 * xv.y + bg * p1.y;
    o.z = a0 * xv.z + bg * p1.z;
    o.w = a0 * xv.w + bg * p1.w;
    out[i] = o;
}

// Pnew = v2*S + v1*P1 + v3*P2 (in place over S); out += beta[k]*gprod*Pnew
__global__ __launch_bounds__(256) void combinek_kernel(float4* __restrict__ S,
                                                       const float4* __restrict__ p1,
                                                       const float4* __restrict__ p2,
                                                       const float* __restrict__ beta,
                                                       const float* __restrict__ gamma,
                                                       float4* __restrict__ out,
                                                       float v1, float v2, float v3,
                                                       int k) {
    int i = blockIdx.x * 256 + threadIdx.x;
    if (i >= ND4) return;
    float g = 1.0f;
    for (int j = 0; j < k; ++j) g *= gamma[j];
    float bk = beta[k] * g;
    float4 sv = S[i];
    float4 a = p1[i];
    float4 b = p2[i];
    float4 pn;
    pn.x = v2 * sv.x + v1 * a.x + v3 * b.x;
    pn.y = v2 * sv.y + v1 * a.y + v3 * b.y;
    pn.z = v2 * sv.z + v1 * a.z + v3 * b.z;
    pn.w = v2 * sv.w + v1 * a.w + v3 * b.w;
    S[i] = pn;
    float4 o = out[i];
    o.x += bk * pn.x;
    o.y += bk * pn.y;
    o.z += bk * pn.z;
    o.w += bk * pn.w;
    out[i] = o;
}

extern "C" void kernel_launch(void* const* d_in, const int* in_sizes, int n_in,
                              void* d_out, int out_size, void* d_ws, size_t ws_size,
                              hipStream_t stream) {
    const float* x = (const float*)d_in[0];
    const float* alpha = (const float*)d_in[1];
    const float* beta = (const float*)d_in[2];
    const float* gamma = (const float*)d_in[3];
    const int* edge = (const int*)d_in[4];
    const int* row = edge;           // edge_index[0]
    const int* col = edge + NE;      // edge_index[1]
    float* out = (float*)d_out;

    // workspace layout
    float* bufA = (float*)d_ws;
    float* bufB = bufA + ND;
    float* bufC = bufB + ND;
    float* nrm = bufC + ND;
    float* dis = nrm + NE;
    int* deg = (int*)(dis + NN);
    float* bufs[3] = {bufA, bufB, bufC};

    // host-side recurrence constants (a = b = 0.5, lmax = 2.0)
    const double a = 0.5, b = 0.5, tl = 2.0 / 2.0;  // tl = 2/lmax
    // L(y) = (tl-1)*y - tl*S(y); with tl=1 this is just -S(y)
    const double c1 = (a - b) / 2.0, c2 = (a + b + 2.0) / 2.0;
    float u1 = (float)(c1 + c2 * (tl - 1.0));
    float u2 = (float)(-c2 * tl);

    const int EB = (NE + 255) / 256;
    const int NB = (NN + 255) / 256;
    const int CB = (ND4 + 255) / 256;
    const int SB = (int)(((long long)NE * 32 + 255) / 256);

    // degree -> dis -> norm
    hipMemsetAsync(deg, 0, NN * sizeof(int), stream);
    deg_kernel<<<EB, 256, 0, stream>>>(row, deg);
    dis_kernel<<<NB, 256, 0, stream>>>(deg, dis);
    norm_kernel<<<EB, 256, 0, stream>>>(row, col, dis, nrm);

    // k = 1: S(x) -> bufA, combine into P1 (in bufA) and init out
    hipMemsetAsync(bufA, 0, (size_t)ND * sizeof(float), stream);
    spmv_kernel<<<SB, 256, 0, stream>>>(row, col, nrm, x, bufA);
    combine1_kernel<<<CB, 256, 0, stream>>>((const float4*)x, (float4*)bufA,
                                            alpha, beta, gamma, (float4*)out, u1, u2);

    // k = 2..10
    for (int k = 2; k <= KMAX; ++k) {
        double dk = (double)k;
        double theta = (2 * dk + a + b) * (2 * dk + a + b - 1) / (2 * dk * (dk + a + b));
        double theta_p = (2 * dk + a + b - 1) * (a * a - b * b) /
                         (2 * dk * (dk + a + b) * (2 * dk + a + b - 2));
        double theta_pp = (dk + a - 1) * (dk + b - 1) * (2 * dk + a + b) /
                          (dk * (dk + a + b) * (2 * dk + a + b - 2));
        float v1 = (float)(theta * (tl - 1.0) + theta_p);
        float v2 = (float)(-theta * tl);
        float v3 = (float)(-theta_pp);

        float* dst = bufs[(k - 1) % 3];
        const float* p1 = bufs[(k - 2) % 3];
        const float* p2 = (k == 2) ? x : bufs[(k - 3) % 3];

        hipMemsetAsync(dst, 0, (size_t)ND * sizeof(float), stream);
        spmv_kernel<<<SB, 256, 0, stream>>>(row, col, nrm, p1, dst);
        combinek_kernel<<<CB, 256, 0, stream>>>((float4*)dst, (const float4*)p1,
                                                (const float4*)p2, beta, gamma,
                                                (float4*)out, v1, v2, v3, k);
    }
}

// Round 2
// 2871.291 us; speedup vs baseline: 19.8711x; 19.8711x over previous
//
#include <hip/hip_runtime.h>

#define NN 100000
#define NE 3200000
#define D 128
#define ND (NN * D)
#define KMAX 10
#define NBLK ((NN + 255) / 256)   // 391 blocks for scan

// ---------------- CSR build ----------------

__global__ __launch_bounds__(256) void deg_kernel(const int* __restrict__ row,
                                                  int* __restrict__ deg) {
    int e = blockIdx.x * 256 + threadIdx.x;
    if (e < NE) atomicAdd(&deg[row[e]], 1);
}

__global__ __launch_bounds__(256) void dis_kernel(const int* __restrict__ deg,
                                                  float* __restrict__ dis) {
    int i = blockIdx.x * 256 + threadIdx.x;
    if (i < NN) {
        int d = deg[i];
        dis[i] = d > 0 ? rsqrtf((float)d) : 0.0f;
    }
}

// per-block exclusive scan of deg -> partial, block totals -> bsum
__global__ __launch_bounds__(256) void scan1_kernel(const int* __restrict__ deg,
                                                    int* __restrict__ partial,
                                                    int* __restrict__ bsum) {
    __shared__ int s[256];
    int t = threadIdx.x;
    int i = blockIdx.x * 256 + t;
    int v = (i < NN) ? deg[i] : 0;
    s[t] = v;
    __syncthreads();
    for (int off = 1; off < 256; off <<= 1) {
        int add = (t >= off) ? s[t - off] : 0;
        __syncthreads();
        s[t] += add;
        __syncthreads();
    }
    if (i < NN) partial[i] = s[t] - v;      // exclusive within block
    if (t == 255) bsum[blockIdx.x] = s[255];
}

// exclusive scan of the 391 block sums (single block, 512-thread ladder)
__global__ __launch_bounds__(512) void scan2_kernel(const int* __restrict__ bsum,
                                                    int* __restrict__ boff) {
    __shared__ int s[512];
    int t = threadIdx.x;
    int v = (t < NBLK) ? bsum[t] : 0;
    s[t] = v;
    __syncthreads();
    for (int off = 1; off < 512; off <<= 1) {
        int add = (t >= off) ? s[t - off] : 0;
        __syncthreads();
        s[t] += add;
        __syncthreads();
    }
    if (t < NBLK) boff[t] = s[t] - v;
}

__global__ __launch_bounds__(256) void scan3_kernel(const int* __restrict__ partial,
                                                    const int* __restrict__ boff,
                                                    int* __restrict__ rowptr) {
    int i = blockIdx.x * 256 + threadIdx.x;
    if (i < NN) rowptr[i] = partial[i] + boff[i >> 8];
    if (i == 0) rowptr[NN] = NE;
}

__global__ __launch_bounds__(256) void fill_kernel(const int* __restrict__ row,
                                                   const int* __restrict__ col,
                                                   const int* __restrict__ rowptr,
                                                   const float* __restrict__ dis,
                                                   int* __restrict__ fillc,
                                                   int* __restrict__ ecol,
                                                   float* __restrict__ enrm) {
    int e = blockIdx.x * 256 + threadIdx.x;
    if (e >= NE) return;
    int r = row[e];
    int c = col[e];
    int idx = atomicAdd(&fillc[r], 1);
    int pos = rowptr[r] + idx;
    ecol[pos] = c;
    enrm[pos] = dis[r] * dis[c];
}

// ---------------- fused SpMV + Jacobi combine ----------------
// One 64-lane wave per row; lane owns float2 slice (64*2 = 128 = D).
// S = Ahat @ y (gather, register accumulate)
// Pk = v1*p1[r] + v2*S + v3*p2[r]
// bk = beta[k] * prod(gamma[0..k-1])
// first: out[r] = alpha[0]*p1[r] + bk*Pk   else: out[r] += bk*Pk
__global__ __launch_bounds__(256) void spmv_fused_kernel(
    const int* __restrict__ rowptr, const int* __restrict__ ecol,
    const float* __restrict__ enrm, const float* __restrict__ y,
    const float* __restrict__ p1, const float* __restrict__ p2,
    const float* __restrict__ alpha, const float* __restrict__ beta,
    const float* __restrict__ gamma, float* __restrict__ dst,
    float* __restrict__ out, float v1, float v2, float v3, int k, int first) {
    int r = blockIdx.x * 4 + (threadIdx.x >> 6);
    if (r >= NN) return;
    int lane = threadIdx.x & 63;

    int j = rowptr[r];
    int end = rowptr[r + 1];
    float sx = 0.0f, sy = 0.0f;
    for (; j + 3 < end; j += 4) {
        int c0 = ecol[j];     int c1 = ecol[j + 1];
        int c2 = ecol[j + 2]; int c3 = ecol[j + 3];
        float w0 = enrm[j];     float w1 = enrm[j + 1];
        float w2 = enrm[j + 2]; float w3 = enrm[j + 3];
        float2 a0 = *(const float2*)(y + (size_t)c0 * D + lane * 2);
        float2 a1 = *(const float2*)(y + (size_t)c1 * D + lane * 2);
        float2 a2 = *(const float2*)(y + (size_t)c2 * D + lane * 2);
        float2 a3 = *(const float2*)(y + (size_t)c3 * D + lane * 2);
        sx = fmaf(w0, a0.x, sx); sy = fmaf(w0, a0.y, sy);
        sx = fmaf(w1, a1.x, sx); sy = fmaf(w1, a1.y, sy);
        sx = fmaf(w2, a2.x, sx); sy = fmaf(w2, a2.y, sy);
        sx = fmaf(w3, a3.x, sx); sy = fmaf(w3, a3.y, sy);
    }
    for (; j < end; ++j) {
        int c = ecol[j];
        float w = enrm[j];
        float2 a = *(const float2*)(y + (size_t)c * D + lane * 2);
        sx = fmaf(w, a.x, sx);
        sy = fmaf(w, a.y, sy);
    }

    size_t off = (size_t)r * D + lane * 2;
    float2 p1v = *(const float2*)(p1 + off);
    float2 p2v = *(const float2*)(p2 + off);
    float pkx = v1 * p1v.x + v2 * sx + v3 * p2v.x;
    float pky = v1 * p1v.y + v2 * sy + v3 * p2v.y;

    float g = 1.0f;
    for (int t = 0; t < k; ++t) g *= gamma[t];
    float bk = beta[k] * g;

    float2 o;
    if (first) {
        float a0 = alpha[0];
        o.x = a0 * p1v.x + bk * pkx;
        o.y = a0 * p1v.y + bk * pky;
    } else {
        float2 ov = *(const float2*)(out + off);
        o.x = ov.x + bk * pkx;
        o.y = ov.y + bk * pky;
    }
    *(float2*)(dst + off) = make_float2(pkx, pky);
    *(float2*)(out + off) = o;
}

extern "C" void kernel_launch(void* const* d_in, const int* in_sizes, int n_in,
                              void* d_out, int out_size, void* d_ws, size_t ws_size,
                              hipStream_t stream) {
    const float* x = (const float*)d_in[0];
    const float* alpha = (const float*)d_in[1];
    const float* beta = (const float*)d_in[2];
    const float* gamma = (const float*)d_in[3];
    const int* edge = (const int*)d_in[4];
    const int* row = edge;        // edge_index[0]
    const int* col = edge + NE;   // edge_index[1]
    float* out = (float*)d_out;

    // workspace layout
    float* bufA = (float*)d_ws;
    float* bufB = bufA + ND;
    float* bufC = bufB + ND;
    float* enrm = bufC + ND;                 // NE
    int* ecol = (int*)(enrm + NE);           // NE
    int* rowptr = ecol + NE;                 // NN+1
    int* partial = rowptr + NN + 1;          // NN
    int* fillc = partial + NN;               // NN
    int* deg = fillc + NN;                   // NN
    float* dis = (float*)(deg + NN);         // NN
    int* bsum = (int*)(dis + NN);            // NBLK
    int* boff = bsum + NBLK;                 // NBLK
    float* bufs[3] = {bufA, bufB, bufC};

    // recurrence constants (a = b = 0.5, lmax = 2.0 -> tl = 1)
    const double a = 0.5, b = 0.5, tl = 1.0;
    const double c1 = (a - b) / 2.0, c2 = (a + b + 2.0) / 2.0;
    float u1 = (float)(c1 + c2 * (tl - 1.0));   // coeff of x in P1
    float u2 = (float)(-c2 * tl);               // coeff of S(x) in P1

    const int EB = (NE + 255) / 256;
    const int NB = (NN + 255) / 256;
    const int SB = (NN + 3) / 4;   // 4 rows per 256-thread block

    // ---- CSR build ----
    hipMemsetAsync(deg, 0, NN * sizeof(int), stream);
    hipMemsetAsync(fillc, 0, NN * sizeof(int), stream);
    deg_kernel<<<EB, 256, 0, stream>>>(row, deg);
    dis_kernel<<<NB, 256, 0, stream>>>(deg, dis);
    scan1_kernel<<<NBLK, 256, 0, stream>>>(deg, partial, bsum);
    scan2_kernel<<<1, 512, 0, stream>>>(bsum, boff);
    scan3_kernel<<<NB, 256, 0, stream>>>(partial, boff, rowptr);
    fill_kernel<<<EB, 256, 0, stream>>>(row, col, rowptr, dis, fillc, ecol, enrm);

    // ---- k = 1: P1 = u1*x + u2*S(x); out = alpha0*x + beta1*gamma0*P1 ----
    spmv_fused_kernel<<<SB, 256, 0, stream>>>(rowptr, ecol, enrm, x, x, x,
                                              alpha, beta, gamma, bufA, out,
                                              u1, u2, 0.0f, 1, 1);

    // ---- k = 2..10 ----
    for (int k = 2; k <= KMAX; ++k) {
        double dk = (double)k;
        double theta = (2 * dk + a + b) * (2 * dk + a + b - 1) / (2 * dk * (dk + a + b));
        double theta_p = (2 * dk + a + b - 1) * (a * a - b * b) /
                         (2 * dk * (dk + a + b) * (2 * dk + a + b - 2));
        double theta_pp = (dk + a - 1) * (dk + b - 1) * (2 * dk + a + b) /
                          (dk * (dk + a + b) * (2 * dk + a + b - 2));
        float v1 = (float)(theta * (tl - 1.0) + theta_p);
        float v2 = (float)(-theta * tl);
        float v3 = (float)(-theta_pp);

        float* dst = bufs[(k - 1) % 3];
        const float* p1 = bufs[(k - 2) % 3];
        const float* p2 = (k == 2) ? x : bufs[(k - 3) % 3];

        spmv_fused_kernel<<<SB, 256, 0, stream>>>(rowptr, ecol, enrm, p1, p1, p2,
                                                  alpha, beta, gamma, dst, out,
                                                  v1, v2, v3, k, 0);
    }
}